// Round 2
// baseline (412.997 us; speedup 1.0000x reference)
//
#include <hip/hip_runtime.h>

#define B_ 128
#define T_ 512
#define NIN_ 12
#define H_ 512
#define NOUT_ 4
#define DT_ 0.001f
#define NSLOT 8  // H_ / 64 neurons per lane

__device__ __forceinline__ float clamp01(float v) { return fminf(fmaxf(v, 0.0f), 1.0f); }

// LDS-tiled transpose of two 512x512 matrices (w_l1_in, w_l1_rec) into workspace.
__global__ void transpose_pair(const float* __restrict__ a,
                               const float* __restrict__ b,
                               float* __restrict__ at,
                               float* __restrict__ bt) {
  __shared__ float tile[32][33];
  const float* src = blockIdx.z ? b : a;
  float* dst = blockIdx.z ? bt : at;
  const int bx = blockIdx.x * 32, by = blockIdx.y * 32;
  const int tx = threadIdx.x, ty = threadIdx.y;  // 32x8
#pragma unroll
  for (int k = 0; k < 32; k += 8)
    tile[ty + k][tx] = src[(size_t)(by + ty + k) * H_ + bx + tx];
  __syncthreads();
#pragma unroll
  for (int k = 0; k < 32; k += 8)
    dst[(size_t)(bx + ty + k) * H_ + by + tx] = tile[tx][ty + k];
}

// One WAVE per batch row. Lane l owns neurons n = s*64 + l for s in [0,8).
// Spike state is exchanged purely via __ballot (wave-uniform u64 masks) —
// no LDS masks, no __syncthreads in the 512-step recurrence.
// Gather indexing: weight element (spike_idx, neuron) at W[spike_idx*rs + neuron*cs].
__global__ __launch_bounds__(64, 1) void snn_wave(
    const float* __restrict__ x,      // [B][T][NIN]
    const float* __restrict__ w_in,   // [H][NIN]
    const float* __restrict__ w_out,  // [NOUT][H]
    const float* __restrict__ W1,     // w_l1_in (maybe transposed)
    const float* __restrict__ WR,     // w_l1_rec (maybe transposed)
    const int rs, const int cs,
    const float* __restrict__ tse, const float* __restrict__ tme,
    const float* __restrict__ ts1, const float* __restrict__ tm1,
    const float* __restrict__ tso, const float* __restrict__ tmo,
    float* __restrict__ out)          // [T][B][NOUT]
{
  const int b = blockIdx.x;
  const int l = threadIdx.x;

  __shared__ float4 xs[T_ * 3];  // whole x[b] as float4 (24 KB)
  const float4* xg = (const float4*)(x + (size_t)b * T_ * NIN_);
  for (int i = l; i < T_ * 3; i += 64) xs[i] = xg[i];

  float win[NSLOT][NIN_];
  float ae[NSLOT], be[NSLOT], a1[NSLOT], b1[NSLOT];
  float ev[NSLOT], ei[NSLOT], v1[NSLOT], i1[NSLOT];
  unsigned long long zprev[NSLOT];

#pragma unroll
  for (int s = 0; s < NSLOT; ++s) {
    const int n = (s << 6) + l;
#pragma unroll
    for (int i = 0; i < NIN_; ++i) win[s][i] = w_in[n * NIN_ + i];
    ae[s] = DT_ * clamp01(tme[n]);
    be[s] = DT_ * clamp01(tse[n]);
    a1[s] = DT_ * clamp01(tm1[n]);
    b1[s] = DT_ * clamp01(ts1[n]);
    ev[s] = 0.f; ei[s] = 0.f; v1[s] = 0.f; i1[s] = 0.f;
    zprev[s] = 0ULL;
  }
  const float ao = DT_ * clamp01(tmo[0]);
  const float bo = DT_ * clamp01(tso[0]);
  float sov = 0.f, soi = 0.f;
  const int o = l & 3;  // output index this lane mirrors (only lanes 0..3 stored)

  __syncthreads();  // once: xs visible (single wave, but keep it safe)

  for (int t = 0; t < T_; ++t) {
    const float4 xa = xs[t * 3 + 0];
    const float4 xb = xs[t * 3 + 1];
    const float4 xc = xs[t * 3 + 2];

    unsigned long long mE[NSLOT], mZ[NSLOT];

#pragma unroll
    for (int s = 0; s < NSLOT; ++s) {
      // encoder input current: x[b,t,:] . w_in[n,:]
      float c = 0.f;
      c = fmaf(xa.x, win[s][0], c);  c = fmaf(xa.y, win[s][1], c);
      c = fmaf(xa.z, win[s][2], c);  c = fmaf(xa.w, win[s][3], c);
      c = fmaf(xb.x, win[s][4], c);  c = fmaf(xb.y, win[s][5], c);
      c = fmaf(xb.z, win[s][6], c);  c = fmaf(xb.w, win[s][7], c);
      c = fmaf(xc.x, win[s][8], c);  c = fmaf(xc.y, win[s][9], c);
      c = fmaf(xc.z, win[s][10], c); c = fmaf(xc.w, win[s][11], c);

      // encoder LIF (norse lif_feed_forward_step)
      const float vdec = ev[s] + ae[s] * (ei[s] - ev[s]);
      const float idec = ei[s] - be[s] * ei[s];
      const bool ze = (vdec - 1.0f) > 0.0f;
      ev[s] = ze ? 0.0f : vdec;
      ei[s] = idec + c;

      // layer-1 decay + spike (uses i1 from previous step)
      const float v1d = v1[s] + a1[s] * (i1[s] - v1[s]);
      const float i1d = i1[s] - b1[s] * i1[s];
      const bool z1 = (v1d - 1.0f) > 0.0f;
      v1[s] = z1 ? 0.0f : v1d;
      i1[s] = i1d;

      mE[s] = __ballot(ze);
      mZ[s] = __ballot(z1);
    }

    // sparse projections: encoder spikes (this step) + recurrent spikes (prev step).
    // Masks are wave-uniform -> scalar branches, no divergence; 8 independent
    // loads per spike (one per slot) keep memory latency overlapped.
#pragma unroll
    for (int s = 0; s < NSLOT; ++s) {
      unsigned long long m = mE[s];
      while (m) {
        const int hs = (s << 6) + __builtin_ctzll(m);
        m &= m - 1;
        const float* row = W1 + (size_t)hs * rs;
#pragma unroll
        for (int q = 0; q < NSLOT; ++q)
          i1[q] += row[(size_t)((q << 6) + l) * cs];
      }
      m = zprev[s];
      while (m) {
        const int js = (s << 6) + __builtin_ctzll(m);
        m &= m - 1;
        const float* row = WR + (size_t)js * rs;
#pragma unroll
        for (int q = 0; q < NSLOT; ++q)
          i1[q] += row[(size_t)((q << 6) + l) * cs];
      }
    }

    // output projection from z1 (this step); all lanes compute o = l&3 copy.
    float oin = 0.f;
#pragma unroll
    for (int s = 0; s < NSLOT; ++s) {
      unsigned long long m = mZ[s];
      while (m) {
        const int js = (s << 6) + __builtin_ctzll(m);
        m &= m - 1;
        oin += w_out[o * H_ + js];
      }
      zprev[s] = mZ[s];
    }

    // LI output cell: v uses OLD i, then i updates with out_in
    sov = sov + ao * (soi - sov);
    soi = soi - bo * soi + oin;
    if (l < NOUT_) out[((size_t)t * B_ + b) * NOUT_ + l] = sov;
  }
}

extern "C" void kernel_launch(void* const* d_in, const int* in_sizes, int n_in,
                              void* d_out, int out_size, void* d_ws, size_t ws_size,
                              hipStream_t stream) {
  const float* x    = (const float*)d_in[0];
  const float* w_in = (const float*)d_in[1];
  const float* w1   = (const float*)d_in[2];
  const float* wrec = (const float*)d_in[3];
  const float* wout = (const float*)d_in[4];
  const float* tse  = (const float*)d_in[5];
  const float* tme  = (const float*)d_in[6];
  const float* ts1  = (const float*)d_in[7];
  const float* tm1  = (const float*)d_in[8];
  const float* tso  = (const float*)d_in[9];
  const float* tmo  = (const float*)d_in[10];
  float* out = (float*)d_out;

  const size_t mat_elems = (size_t)H_ * H_;
  if (ws_size >= 2 * mat_elems * sizeof(float)) {
    // Transposed weight tables -> per-spike reads are coalesced rows.
    float* W1t = (float*)d_ws;
    float* WRt = W1t + mat_elems;
    transpose_pair<<<dim3(16, 16, 2), dim3(32, 8), 0, stream>>>(w1, wrec, W1t, WRt);
    snn_wave<<<dim3(B_), dim3(64), 0, stream>>>(
        x, w_in, wout, W1t, WRt, H_, 1,
        tse, tme, ts1, tm1, tso, tmo, out);
  } else {
    // Fallback: original layout (uncoalesced per-spike reads, still correct).
    snn_wave<<<dim3(B_), dim3(64), 0, stream>>>(
        x, w_in, wout, w1, wrec, 1, H_,
        tse, tme, ts1, tm1, tso, tmo, out);
  }
}

// Round 3
// 258.004 us; speedup vs baseline: 1.6007x; 1.6007x over previous
//
#include <hip/hip_runtime.h>

#define B_ 128
#define T_ 512
#define NIN_ 12
#define H_ 512
#define NOUT_ 4
#define DT_ 0.001f

typedef unsigned long long ull;

// Persistent device scratch (rewritten in full every kernel_launch -> graph-safe).
__device__ float g_W1t[H_ * H_];          // g_W1t[h][n] = w_l1_in[n][h]
__device__ float g_WRt[H_ * H_];          // g_WRt[h][n] = w_l1_rec[n][h]
__device__ ull   g_masks[B_ * T_ * 8];    // encoder spike ballots; bit j of slot s = neuron 8j+s

__device__ __forceinline__ float clamp01(float v) { return fminf(fmaxf(v, 0.0f), 1.0f); }

// LDS-tiled transpose of w_l1_in / w_l1_rec into device globals.
__global__ void transpose_pair(const float* __restrict__ a, const float* __restrict__ bsrc) {
  __shared__ float tile[32][33];
  const float* src = blockIdx.z ? bsrc : a;
  float* dst = blockIdx.z ? g_WRt : g_W1t;
  const int bx = blockIdx.x * 32, by = blockIdx.y * 32;
  const int tx = threadIdx.x, ty = threadIdx.y;  // 32x8
#pragma unroll
  for (int k = 0; k < 32; k += 8)
    tile[ty + k][tx] = src[(size_t)(by + ty + k) * H_ + bx + tx];
  __syncthreads();
#pragma unroll
  for (int k = 0; k < 32; k += 8)
    dst[(size_t)(bx + ty + k) * H_ + by + tx] = tile[tx][ty + k];
}

// Phase 1: encoder LIF, fully parallel across (b, h). One thread = one neuron.
// grid (B, 2) x block 256: wave w of block-half g owns slot s = g*4+w, lane j -> neuron n = 8j+s.
// Writes per-step spike ballots to g_masks[((b*T)+t)*8 + s].
__global__ __launch_bounds__(256, 1) void snn_phase1(
    const float* __restrict__ x, const float* __restrict__ w_in,
    const float* __restrict__ tse, const float* __restrict__ tme) {
  const int b = blockIdx.x;
  const int g = blockIdx.y;
  const int w = threadIdx.x >> 6;
  const int j = threadIdx.x & 63;
  const int s = g * 4 + w;
  const int n = (j << 3) + s;

  __shared__ float4 xs[T_ * 3];  // 24 KB: whole x[b]
  const float4* xg = (const float4*)(x + (size_t)b * T_ * NIN_);
  for (int i = threadIdx.x; i < T_ * 3; i += 256) xs[i] = xg[i];

  float win[NIN_];
#pragma unroll
  for (int i = 0; i < NIN_; ++i) win[i] = w_in[n * NIN_ + i];
  const float ae = DT_ * clamp01(tme[n]);
  const float be = DT_ * clamp01(tse[n]);
  float ev = 0.f, ei = 0.f;
  ull* mout = g_masks + (size_t)b * T_ * 8 + s;
  __syncthreads();

#pragma unroll 4
  for (int t = 0; t < T_; ++t) {
    const float4 xa = xs[t * 3 + 0], xb = xs[t * 3 + 1], xc = xs[t * 3 + 2];
    float c = 0.f;
    c = fmaf(xa.x, win[0], c);  c = fmaf(xa.y, win[1], c);
    c = fmaf(xa.z, win[2], c);  c = fmaf(xa.w, win[3], c);
    c = fmaf(xb.x, win[4], c);  c = fmaf(xb.y, win[5], c);
    c = fmaf(xb.z, win[6], c);  c = fmaf(xb.w, win[7], c);
    c = fmaf(xc.x, win[8], c);  c = fmaf(xc.y, win[9], c);
    c = fmaf(xc.z, win[10], c); c = fmaf(xc.w, win[11], c);

    const float vdec = ev + ae * (ei - ev);
    const float idec = ei - be * ei;
    const bool ze = (vdec - 1.0f) > 0.0f;
    ev = ze ? 0.0f : vdec;
    ei = idec + c;
    const ull m = __ballot(ze);
    if (j == 0) mout[(size_t)t * 8] = m;
  }
}

// Phase 2: layer-1 LIF recurrence + LI output. One wave per batch row.
// Lane l owns neurons n = 8l+s, s in [0,8). Encoder spike masks are read with
// wave-uniform (scalar) loads, prefetched one step ahead; fast path has zero
// data-dependent VMEM. Spike gathers read 2x float4 per lane (coalesced rows).
__global__ __launch_bounds__(64, 1) void snn_phase2(
    const float* __restrict__ w_out,
    const float* __restrict__ ts1, const float* __restrict__ tm1,
    const float* __restrict__ tso, const float* __restrict__ tmo,
    float* __restrict__ out) {
  const int b = blockIdx.x;
  const int l = threadIdx.x;

  float a1[8], b1v[8], v1[8], i1[8];
#pragma unroll
  for (int s = 0; s < 8; ++s) {
    const int n = (l << 3) + s;
    a1[s] = DT_ * clamp01(tm1[n]);
    b1v[s] = DT_ * clamp01(ts1[n]);
    v1[s] = 0.f; i1[s] = 0.f;
  }
  const float ao = DT_ * clamp01(tmo[0]);
  const float bo = DT_ * clamp01(tso[0]);
  float sov = 0.f, soi = 0.f;
  const int o = l & 3;
  const float* wo = w_out + o * H_;

  ull zp[8];
#pragma unroll
  for (int s = 0; s < 8; ++s) zp[s] = 0ULL;

  const ull* __restrict__ mb = g_masks + (size_t)b * T_ * 8;
  ull c[8];
#pragma unroll
  for (int k = 0; k < 8; ++k) c[k] = mb[k];

  for (int t = 0; t < T_; ++t) {
    // prefetch next step's masks (uniform address -> SMEM; hidden under this step)
    ull nx[8];
    const int tn = (t + 1 < T_) ? t + 1 : t;
#pragma unroll
    for (int k = 0; k < 8; ++k) nx[k] = mb[(size_t)tn * 8 + k];

    // layer-1 LIF decay + spike (state from t-1)
    ull mz[8];
#pragma unroll
    for (int s = 0; s < 8; ++s) {
      const float vd = v1[s] + a1[s] * (i1[s] - v1[s]);
      const float id = i1[s] - b1v[s] * i1[s];
      const bool z = (vd - 1.0f) > 0.0f;
      v1[s] = z ? 0.0f : vd;
      i1[s] = id;
      mz[s] = __ballot(z);
    }

    // encoder drive: i1[n] += sum over spiking hs of W1t[hs][n]
    const ull anyE = c[0] | c[1] | c[2] | c[3] | c[4] | c[5] | c[6] | c[7];
    if (anyE) {
#pragma unroll
      for (int s = 0; s < 8; ++s) {
        ull m = c[s];
        while (m) {
          const int jj = __builtin_ctzll(m);
          m &= m - 1;
          const int hs = (jj << 3) + s;
          const float4* r = (const float4*)(g_W1t + (size_t)hs * H_);
          const float4 ra = r[2 * l], rb = r[2 * l + 1];
          i1[0] += ra.x; i1[1] += ra.y; i1[2] += ra.z; i1[3] += ra.w;
          i1[4] += rb.x; i1[5] += rb.y; i1[6] += rb.z; i1[7] += rb.w;
        }
      }
    }
    // recurrent drive from z1 of previous step
    const ull anyR = zp[0] | zp[1] | zp[2] | zp[3] | zp[4] | zp[5] | zp[6] | zp[7];
    if (anyR) {
#pragma unroll
      for (int s = 0; s < 8; ++s) {
        ull m = zp[s];
        while (m) {
          const int jj = __builtin_ctzll(m);
          m &= m - 1;
          const int js = (jj << 3) + s;
          const float4* r = (const float4*)(g_WRt + (size_t)js * H_);
          const float4 ra = r[2 * l], rb = r[2 * l + 1];
          i1[0] += ra.x; i1[1] += ra.y; i1[2] += ra.z; i1[3] += ra.w;
          i1[4] += rb.x; i1[5] += rb.y; i1[6] += rb.z; i1[7] += rb.w;
        }
      }
    }

    // output projection from z1 of THIS step
    float oin = 0.f;
    const ull anyZ = mz[0] | mz[1] | mz[2] | mz[3] | mz[4] | mz[5] | mz[6] | mz[7];
    if (anyZ) {
#pragma unroll
      for (int s = 0; s < 8; ++s) {
        ull m = mz[s];
        while (m) {
          const int jj = __builtin_ctzll(m);
          m &= m - 1;
          oin += wo[(jj << 3) + s];
        }
      }
    }

    // LI output cell: v uses OLD i, then i updates with out_in
    sov = sov + ao * (soi - sov);
    soi = soi - bo * soi + oin;
    if (l < NOUT_) out[((size_t)t * B_ + b) * NOUT_ + l] = sov;

#pragma unroll
    for (int s = 0; s < 8; ++s) { zp[s] = mz[s]; c[s] = nx[s]; }
  }
}

extern "C" void kernel_launch(void* const* d_in, const int* in_sizes, int n_in,
                              void* d_out, int out_size, void* d_ws, size_t ws_size,
                              hipStream_t stream) {
  const float* x    = (const float*)d_in[0];
  const float* w_in = (const float*)d_in[1];
  const float* w1   = (const float*)d_in[2];
  const float* wrec = (const float*)d_in[3];
  const float* wout = (const float*)d_in[4];
  const float* tse  = (const float*)d_in[5];
  const float* tme  = (const float*)d_in[6];
  const float* ts1  = (const float*)d_in[7];
  const float* tm1  = (const float*)d_in[8];
  const float* tso  = (const float*)d_in[9];
  const float* tmo  = (const float*)d_in[10];
  float* out = (float*)d_out;

  transpose_pair<<<dim3(16, 16, 2), dim3(32, 8), 0, stream>>>(w1, wrec);
  snn_phase1<<<dim3(B_, 2), dim3(256), 0, stream>>>(x, w_in, tse, tme);
  snn_phase2<<<dim3(B_), dim3(64), 0, stream>>>(wout, ts1, tm1, tso, tmo, out);
}